// Round 3
// baseline (712.240 us; speedup 1.0000x reference)
//
#include <hip/hip_runtime.h>
#include <hip/hip_bf16.h>
#include <stdint.h>

#define NN 512
#define HD 128

typedef __attribute__((ext_vector_type(8))) short bf16x8;
typedef __attribute__((ext_vector_type(4))) float f32x4;

static __device__ __forceinline__ float bf2f(unsigned short u) {
  union { uint32_t u32; float f; } cv; cv.u32 = ((uint32_t)u) << 16; return cv.f;
}
static __device__ __forceinline__ unsigned short f2bf(float f) {
  union { float f; uint32_t u; } cv; cv.f = f;
  return (unsigned short)((cv.u + 0x7FFFu + ((cv.u >> 16) & 1u)) >> 16);
}
// packed f32x2 -> bf16x2 (RNE), lo = first arg
static __device__ __forceinline__ uint32_t cvtpk(float lo, float hi) {
  uint32_t r;
  asm("v_cvt_pk_bf16_f32 %0, %1, %2" : "=v"(r) : "v"(lo), "v"(hi));
  return r;
}

struct DetectArgs { const uint16_t* p[10]; int n[10]; };

// Per-tensor dtype sniffing (flags[ti]=1 -> fp32, 0 -> bf16).
__global__ __launch_bounds__(256) void detect_kernel(DetectArgs a, int* __restrict__ flags) {
  __shared__ int acc[256];
  const int ti = blockIdx.x;
  int n = a.n[ti]; if (n > 2048) n = 2048;
  int g = 0;
  for (int w = threadIdx.x; w < n; w += 256) {
    uint16_t v = a.p[ti][w];
    int e = (v >> 7) & 0xFF;
    g += (v == 0u || (e >= 90 && e <= 133)) ? 1 : 0;
  }
  acc[threadIdx.x] = g;
  __syncthreads();
  for (int s = 128; s > 0; s >>= 1) {
    if (threadIdx.x < s) acc[threadIdx.x] += acc[threadIdx.x + s];
    __syncthreads();
  }
  if (threadIdx.x == 0) flags[ti] = (acc[0] * 10 < n * 9) ? 1 : 0;
}

__global__ __launch_bounds__(256) void mask_bias_kernel(const uint32_t* __restrict__ raw,
                                                        float* __restrict__ mbias, int count) {
  int inspect = count >> 2; if (inspect > 256) inspect = 256;
  bool ok_i32 = true, ok_f32 = true, ok_bf16 = true;
  #pragma unroll 1
  for (int w = 0; w < inspect; ++w) {
    uint32_t v = raw[w];
    if (v > 1u) ok_i32 = false;
    if (!(v == 0u || v == 0x3F800000u)) ok_f32 = false;
    uint32_t lo = v & 0xFFFFu, hi = v >> 16;
    if (!((lo == 0u || lo == 0x3F80u) && (hi == 0u || hi == 0x3F80u))) ok_bf16 = false;
  }
  int idx = blockIdx.x * 256 + threadIdx.x;
  if (idx < count) {
    bool on;
    if (ok_i32 || ok_f32) on = raw[idx] != 0u;
    else if (ok_bf16)     on = ((const uint16_t*)raw)[idx] != 0u;
    else                  on = ((const uint8_t*)raw)[idx] != 0u;
    mbias[idx] = on ? 0.0f : -1e30f;
  }
}

// qkv = x @ Wqkv + bqkv ; q linear, k PERMUTED within-row ((c&15)*8 + c>>4) so
// gat_main's frag gather is one bf16x8 load, v TRANSPOSED (vT[b][c][j]) so the
// node MFMA B-fragments are contiguous bf16x8 loads.
__global__ __launch_bounds__(128) void qkv_kernel(const void* __restrict__ xp,
                                                  const void* __restrict__ Wp,
                                                  const void* __restrict__ bp,
                                                  const int* __restrict__ flags,
                                                  uint16_t* __restrict__ qf,
                                                  uint16_t* __restrict__ kf,
                                                  uint16_t* __restrict__ vf) {
  const int f_x = flags[0], f_W = flags[2], f_b = flags[3];
  const int row = blockIdx.x;
  const int t = threadIdx.x;
  __shared__ float xs[HD];
  xs[t] = f_x ? ((const float*)xp)[row * HD + t] : bf2f(((const uint16_t*)xp)[row * HD + t]);
  __syncthreads();
  float aq = 0.f, ak = 0.f, av = 0.f;
  if (f_W) {
    const float* W = (const float*)Wp;
    #pragma unroll 4
    for (int kk = 0; kk < HD; ++kk) {
      float xv = xs[kk]; const float* wr = W + kk * 384;
      aq = fmaf(xv, wr[t], aq);
      ak = fmaf(xv, wr[128 + t], ak);
      av = fmaf(xv, wr[256 + t], av);
    }
  } else {
    const uint16_t* W = (const uint16_t*)Wp;
    #pragma unroll 4
    for (int kk = 0; kk < HD; ++kk) {
      float xv = xs[kk]; const uint16_t* wr = W + kk * 384;
      aq = fmaf(xv, bf2f(wr[t]), aq);
      ak = fmaf(xv, bf2f(wr[128 + t]), ak);
      av = fmaf(xv, bf2f(wr[256 + t]), av);
    }
  }
  float bq = f_b ? ((const float*)bp)[t]       : bf2f(((const uint16_t*)bp)[t]);
  float bk = f_b ? ((const float*)bp)[128 + t] : bf2f(((const uint16_t*)bp)[128 + t]);
  float bv = f_b ? ((const float*)bp)[256 + t] : bf2f(((const uint16_t*)bp)[256 + t]);
  qf[row * HD + t] = f2bf(aq + bq);
  kf[row * HD + ((t & 15) << 3) + (t >> 4)] = f2bf(ak + bk);
  vf[((size_t)((row >> 9) * HD + t)) * NN + (row & (NN - 1))] = f2bf(av + bv);
}

// One block per (b,i); 8 waves, wave w owns bands {w, w+8, w+16, w+24}.
// R3: all 36 B-fragments (GEMM1 We*q, GEMM2 Weo) live in REGISTERS (loaded
// once via a reused LDS build pool); raw tile processed in two K-halves so
// per-wave scratch is 2.3 KB -> LDS 34 KB -> 4 blocks/CU (8 waves/SIMD, grid
// 1024 = 256x4, no tail). raw writes use tl^quad block swizzle (kills the
// 2.49M 4-way bank conflicts). cvt_pk bf16 packing. node = att@v via MFMA
// (head-indicator rows, B-frags from transposed vf).
__global__ __launch_bounds__(512, 6) void gat_main_kernel(
    const void* __restrict__ eap,
    const void* __restrict__ Wep,  const void* __restrict__ bep,
    const void* __restrict__ Wnop, const void* __restrict__ bnop,
    const void* __restrict__ Weop, const void* __restrict__ beop,
    const int* __restrict__ flags,
    const uint16_t* __restrict__ qf, const uint16_t* __restrict__ kf,
    const uint16_t* __restrict__ vf, const float* __restrict__ mbias,
    float* __restrict__ node_out, float* __restrict__ edge_out) {
  const int tid = threadIdx.x;
  const int w = tid >> 6, lane = tid & 63;
  const int l15 = lane & 15, quad = lane >> 4;
  const int bb = blockIdx.x >> 9;
  const int i  = blockIdx.x & (NN - 1);
  const int f_ea = flags[1], f_We = flags[4], f_be = flags[5];
  const int f_Wno = flags[6], f_bno = flags[7], f_Weo = flags[8], f_beo = flags[9];

  // Shared pool: build B1 frags (16 KB), then B2 frags (16 KB), then per-wave
  // raw scratch 8 x 2304 B (16 rows x 72 u16, half-K + pad) = 18.4 KB; also
  // reduction scratch in the tail. Persistent: BLf logit tile, att, vectors.
  __shared__ __align__(16) uint16_t pool[10240];            // 20480 B
  __shared__ __align__(16) uint16_t BLf[4 * 64 * 8];        // 4 KB logit tile
  __shared__ __align__(16) uint16_t att_s[8 * 520];         // [h][j] pad 8 -> 8320 B
  __shared__ __align__(16) float q_s[HD];
  __shared__ __align__(16) float beq_s[HD];
  __shared__ __align__(16) float beo_s[64];
  __shared__ __align__(16) float node_s[HD];

  if (tid < HD) q_s[tid] = bf2f(qf[(bb * NN + i) * HD + tid]);
  if (tid >= 128 && tid < 192) {
    int c = tid - 128;
    beo_s[c] = f_beo ? ((const float*)beop)[c] : bf2f(((const uint16_t*)beop)[c]);
  }
  // logit head-indicator tile: B[k][h] = (k>>4 == h), frag slot = s*64+ln
  if (tid < 256) {
    const int s = tid >> 6, ln = tid & 63;
    const int head = s * 2 + ((ln >> 5) & 1);
    const short v = ((ln & 15) == head) ? (short)0x3F80 : (short)0;
    bf16x8 fr;
    #pragma unroll
    for (int e = 0; e < 8; ++e) fr[e] = v;
    *(bf16x8*)&BLf[(s * 64 + ln) * 8] = fr;
  }
  __syncthreads();

  if (tid < HD) {
    float b = f_be ? ((const float*)bep)[tid] : bf2f(((const uint16_t*)bep)[tid]);
    beq_s[tid] = b * q_s[tid];
  }
  // phase A: build B1 frags (element = We[k][c]*q[c]) into pool
  for (int slot = tid; slot < 1024; slot += 512) {
    const int t = slot >> 7, s = (slot >> 6) & 1, ln = slot & 63;
    const int c = t * 16 + (ln & 15);
    const int k0 = s * 32 + (ln >> 4) * 8;
    const float qc = q_s[c];
    bf16x8 fr;
    if (f_We) {
      const float* W = (const float*)Wep;
      #pragma unroll
      for (int e = 0; e < 8; ++e) fr[e] = (short)f2bf(W[(k0 + e) * HD + c] * qc);
    } else {
      const uint16_t* W = (const uint16_t*)Wep;
      #pragma unroll
      for (int e = 0; e < 8; ++e) fr[e] = (short)f2bf(bf2f(W[(k0 + e) * HD + c]) * qc);
    }
    *(bf16x8*)&pool[slot * 8] = fr;
  }
  __syncthreads();
  bf16x8 B1r[16];
  #pragma unroll
  for (int f = 0; f < 16; ++f) B1r[f] = *(const bf16x8*)&pool[(f * 64 + lane) * 8];
  float beq_r[8], beo_r[4];
  #pragma unroll
  for (int t = 0; t < 8; ++t) beq_r[t] = beq_s[t * 16 + l15];
  #pragma unroll
  for (int t2 = 0; t2 < 4; ++t2) beo_r[t2] = beo_s[t2 * 16 + l15];
  __syncthreads();
  // phase B: build B2 frags (Weo) into pool
  for (int slot = tid; slot < 1024; slot += 512) {
    const int t2 = slot >> 8, s = (slot >> 6) & 3, ln = slot & 63;
    const int c = t2 * 16 + (ln & 15);
    const int k0 = s * 32 + ((ln >> 4) & 3) * 8;
    bf16x8 fr;
    if (f_Weo) {
      const float* W = (const float*)Weop;
      #pragma unroll
      for (int e = 0; e < 8; ++e) fr[e] = (short)f2bf(W[(k0 + e) * 64 + c]);
    } else {
      const uint16_t* W = (const uint16_t*)Weop;
      #pragma unroll
      for (int e = 0; e < 8; ++e) fr[e] = (short)W[(k0 + e) * 64 + c];
    }
    *(bf16x8*)&pool[slot * 8] = fr;
  }
  __syncthreads();
  bf16x8 B2r[16];
  #pragma unroll
  for (int f = 0; f < 16; ++f) B2r[f] = *(const bf16x8*)&pool[(f * 64 + lane) * 8];
  __syncthreads();   // all waves loaded frags; pool now free as raw scratch

  const size_t io_base = (size_t)(bb * NN + i) * NN * 64;   // elements
  const uint16_t* kperm = kf + (size_t)bb * NN * HD;        // permuted rows
  const float* mrow = mbias + bb * NN;
  uint16_t* rws = pool + w * 1152;                          // 16 x 72 u16
  float*    fws = (float*)rws;                              // 16 x 36 f32 (alias)

  auto body = [&](int band, const bf16x8* A1) {
    const int j0 = band * 16;
    const f32x4 mr = *(const f32x4*)(mrow + j0 + quad * 4);
    bf16x8 k8[4];
    #pragma unroll
    for (int r = 0; r < 4; ++r)
      k8[r] = *(const bf16x8*)(kperm + (size_t)(j0 + quad * 4 + r) * HD + l15 * 8);

    f32x4 acc2[4];
    #pragma unroll
    for (int t2 = 0; t2 < 4; ++t2) {
      const float bv = beo_r[t2];
      acc2[t2] = (f32x4){bv, bv, bv, bv};
    }
    f32x4 aL = {0.f, 0.f, 0.f, 0.f};

    #pragma unroll
    for (int h = 0; h < 2; ++h) {
      // ---- GEMM1 half: tiles t = h*4 .. h*4+3 ; raw = k .* e_q -> LDS ----
      #pragma unroll
      for (int tl = 0; tl < 4; ++tl) {
        const int t = h * 4 + tl;
        const float bv = beq_r[t];
        f32x4 a = {bv, bv, bv, bv};
        a = __builtin_amdgcn_mfma_f32_16x16x32_bf16(A1[0], B1r[t * 2 + 0], a, 0, 0, 0);
        a = __builtin_amdgcn_mfma_f32_16x16x32_bf16(A1[1], B1r[t * 2 + 1], a, 0, 0, 0);
        const float v0 = a[0] * bf2f((unsigned short)k8[0][t]);
        const float v1 = a[1] * bf2f((unsigned short)k8[1][t]);
        const float v2 = a[2] * bf2f((unsigned short)k8[2][t]);
        const float v3 = a[3] * bf2f((unsigned short)k8[3][t]);
        const uint32_t p01 = cvtpk(v0, v1), p23 = cvtpk(v2, v3);
        // block swizzle tl^quad: conflict-free b16 writes (banks {0,8,16,24})
        uint16_t* rp = &rws[(tl ^ quad) * 16 + l15];
        rp[(quad * 4 + 0) * 72] = (uint16_t)p01;
        rp[(quad * 4 + 1) * 72] = (uint16_t)(p01 >> 16);
        rp[(quad * 4 + 2) * 72] = (uint16_t)p23;
        rp[(quad * 4 + 3) * 72] = (uint16_t)(p23 >> 16);
      }
      // ---- A2 frags (un-swizzle) ; accumulate GEMM2 + logits ----
      #pragma unroll
      for (int sl = 0; sl < 2; ++sl) {
        const int s = h * 2 + sl;
        const int blk = (sl * 2 + (quad >> 1)) ^ (l15 >> 2);
        const bf16x8 A2 = *(const bf16x8*)&rws[l15 * 72 + blk * 16 + (quad & 1) * 8];
        aL = __builtin_amdgcn_mfma_f32_16x16x32_bf16(A2, *(const bf16x8*)&BLf[(s * 64 + lane) * 8], aL, 0, 0, 0);
        #pragma unroll
        for (int t2 = 0; t2 < 4; ++t2)
          acc2[t2] = __builtin_amdgcn_mfma_f32_16x16x32_bf16(A2, B2r[t2 * 4 + s], acc2[t2], 0, 0, 0);
      }
    }

    // ---- logits ----
    if (l15 < 8) {
      #pragma unroll
      for (int r = 0; r < 4; ++r)
        att_s[l15 * 520 + (j0 + quad * 4 + r)] = f2bf(aL[r] * 0.25f + mr[r]);
    }

    // ---- edge_out: stage f32 per col-half, write 128B-aligned full chunks ----
    #pragma unroll
    for (int ch = 0; ch < 2; ++ch) {
      #pragma unroll
      for (int t2l = 0; t2l < 2; ++t2l) {
        const int t2 = ch * 2 + t2l;
        #pragma unroll
        for (int r = 0; r < 4; ++r)
          fws[(quad * 4 + r) * 36 + t2l * 16 + l15] = acc2[t2][r];
      }
      #pragma unroll
      for (int rg = 0; rg < 2; ++rg) {
        const int row = rg * 8 + (lane >> 3);
        f32x4 vv = *(const f32x4*)&fws[row * 36 + (lane & 7) * 4];
        __builtin_nontemporal_store(vv,
            (f32x4*)(edge_out + io_base + (size_t)(j0 + row) * 64 + ch * 32) + (lane & 7));
      }
    }
  };

  if (f_ea) {
    // fp32 edge_attr: pipeline raw f32x4 loads one band ahead, convert late.
    f32x4 ef[4];
    {
      const float* ea = (const float*)eap + io_base + (size_t)(w * 16 + l15) * 64 + quad * 8;
      ef[0] = __builtin_nontemporal_load((const f32x4*)ea);
      ef[1] = __builtin_nontemporal_load((const f32x4*)(ea + 4));
      ef[2] = __builtin_nontemporal_load((const f32x4*)(ea + 32));
      ef[3] = __builtin_nontemporal_load((const f32x4*)(ea + 36));
    }
    #pragma unroll
    for (int bi = 0; bi < 4; ++bi) {
      const int band = w + bi * 8;
      f32x4 efn[4];
      if (bi < 3) {
        const float* ea = (const float*)eap + io_base + (size_t)((band + 8) * 16 + l15) * 64 + quad * 8;
        efn[0] = __builtin_nontemporal_load((const f32x4*)ea);
        efn[1] = __builtin_nontemporal_load((const f32x4*)(ea + 4));
        efn[2] = __builtin_nontemporal_load((const f32x4*)(ea + 32));
        efn[3] = __builtin_nontemporal_load((const f32x4*)(ea + 36));
      }
      bf16x8 A1[2];
      #pragma unroll
      for (int s = 0; s < 2; ++s) {
        union { bf16x8 v; uint32_t u[4]; } cv;
        cv.u[0] = cvtpk(ef[2 * s][0], ef[2 * s][1]);
        cv.u[1] = cvtpk(ef[2 * s][2], ef[2 * s][3]);
        cv.u[2] = cvtpk(ef[2 * s + 1][0], ef[2 * s + 1][1]);
        cv.u[3] = cvtpk(ef[2 * s + 1][2], ef[2 * s + 1][3]);
        A1[s] = cv.v;
      }
      body(band, A1);
      if (bi < 3) {
        #pragma unroll
        for (int s = 0; s < 4; ++s) ef[s] = efn[s];
      }
    }
  } else {
    bf16x8 eb[2];
    {
      const uint16_t* ea = (const uint16_t*)eap + io_base + (size_t)(w * 16 + l15) * 64 + quad * 8;
      eb[0] = __builtin_nontemporal_load((const bf16x8*)ea);
      eb[1] = __builtin_nontemporal_load((const bf16x8*)(ea + 32));
    }
    #pragma unroll
    for (int bi = 0; bi < 4; ++bi) {
      const int band = w + bi * 8;
      bf16x8 ebn[2];
      if (bi < 3) {
        const uint16_t* ea = (const uint16_t*)eap + io_base + (size_t)((band + 8) * 16 + l15) * 64 + quad * 8;
        ebn[0] = __builtin_nontemporal_load((const bf16x8*)ea);
        ebn[1] = __builtin_nontemporal_load((const bf16x8*)(ea + 32));
      }
      body(band, eb);
      if (bi < 3) { eb[0] = ebn[0]; eb[1] = ebn[1]; }
    }
  }
  __syncthreads();

  // ---- softmax over j: wave w owns head w; shuffle reductions ----
  {
    float vals[8];
    float m = -3.4e38f;
    #pragma unroll
    for (int it = 0; it < 8; ++it)
      m = fmaxf(m, bf2f(att_s[w * 520 + it * 64 + lane]));
    #pragma unroll
    for (int off = 32; off; off >>= 1) m = fmaxf(m, __shfl_xor(m, off));
    float ssum = 0.f;
    #pragma unroll
    for (int it = 0; it < 8; ++it) {
      float v = __expf(bf2f(att_s[w * 520 + it * 64 + lane]) - m);
      vals[it] = v; ssum += v;
    }
    #pragma unroll
    for (int off = 32; off; off >>= 1) ssum += __shfl_xor(ssum, off);
    const float inv = 1.0f / ssum;
    #pragma unroll
    for (int it = 0; it < 8; ++it)
      att_s[w * 520 + it * 64 + lane] = f2bf(vals[it] * inv);
  }
  __syncthreads();   // all heads final; pool free for reductions

  // ---- node = att @ v via MFMA: wave w covers j in [w*64, w*64+64) ----
  // A rows m: att[m&7][...]; n-tile t needs only row m=t (head t, cols t*16+..)
  {
    f32x4 nacc[8];
    #pragma unroll
    for (int t = 0; t < 8; ++t) nacc[t] = (f32x4){0.f, 0.f, 0.f, 0.f};
    const uint16_t* vbase = vf + (size_t)bb * HD * NN;
    #pragma unroll
    for (int ks = 0; ks < 2; ++ks) {
      const int k0 = w * 64 + ks * 32;
      const bf16x8 Af = *(const bf16x8*)&att_s[(l15 & 7) * 520 + k0 + quad * 8];
      #pragma unroll
      for (int t = 0; t < 8; ++t) {
        const bf16x8 Bf = *(const bf16x8*)(vbase + (size_t)(t * 16 + l15) * NN + k0 + quad * 8);
        nacc[t] = __builtin_amdgcn_mfma_f32_16x16x32_bf16(Af, Bf, nacc[t], 0, 0, 0);
      }
    }
    float* red = (float*)pool;             // 8 x 128 f32 = 4 KB
    #pragma unroll
    for (int t = 0; t < 8; ++t)
      if (quad == (t >> 2)) red[w * 128 + t * 16 + l15] = nacc[t][t & 3];
    __syncthreads();
    if (tid < HD) {
      float s = 0.f;
      #pragma unroll
      for (int w2 = 0; w2 < 8; ++w2) s += red[w2 * 128 + tid];
      node_s[tid] = s;
    }
    __syncthreads();
  }

  // ---- node_out = node @ Wno + bno (512-thread split GEMV) ----
  {
    const int c = tid & 127, part = tid >> 7;
    float acc = 0.f;
    if (f_Wno) {
      const float* W = (const float*)Wnop;
      #pragma unroll 8
      for (int kk = part * 32; kk < part * 32 + 32; ++kk)
        acc = fmaf(node_s[kk], W[kk * HD + c], acc);
    } else {
      const uint16_t* W = (const uint16_t*)Wnop;
      #pragma unroll 8
      for (int kk = part * 32; kk < part * 32 + 32; ++kk)
        acc = fmaf(node_s[kk], bf2f(W[kk * HD + c]), acc);
    }
    float* red2 = (float*)pool + 1024;     // 512 f32 = 2 KB
    red2[tid] = acc;
    __syncthreads();
    if (tid < HD) {
      float b = f_bno ? ((const float*)bnop)[tid] : bf2f(((const uint16_t*)bnop)[tid]);
      float r = red2[tid] + red2[128 + tid] + red2[256 + tid] + red2[384 + tid] + b;
      node_out[(bb * NN + i) * HD + tid] = r;
    }
  }
}

extern "C" void kernel_launch(void* const* d_in, const int* in_sizes, int n_in,
                              void* d_out, int out_size, void* d_ws, size_t ws_size,
                              hipStream_t stream) {
  const int b = in_sizes[0] / (NN * HD);   // = 2
  const int rows = b * NN;                 // = 1024

  int*   flags = (int*)d_ws;                                        // 16 ints
  float* mbias = (float*)((char*)d_ws + 64);                        // rows floats
  uint16_t* qf = (uint16_t*)((char*)d_ws + 64 + 4096);
  uint16_t* kf = qf + (size_t)rows * HD;
  uint16_t* vf = kf + (size_t)rows * HD;                            // transposed [b][c][j]

  float* node_out = (float*)d_out;
  float* edge_out = node_out + (size_t)rows * HD;

  DetectArgs da;
  const int float_idx[10] = {0, 1, 3, 4, 5, 6, 7, 8, 9, 10};
  for (int t = 0; t < 10; ++t) {
    da.p[t] = (const uint16_t*)d_in[float_idx[t]];
    da.n[t] = in_sizes[float_idx[t]];
  }

  detect_kernel<<<10, 256, 0, stream>>>(da, flags);
  mask_bias_kernel<<<(rows + 255) / 256, 256, 0, stream>>>((const uint32_t*)d_in[2], mbias, rows);
  qkv_kernel<<<rows, 128, 0, stream>>>(d_in[0], d_in[3], d_in[4], flags, qf, kf, vf);
  gat_main_kernel<<<rows, 512, 0, stream>>>(d_in[1], d_in[5], d_in[6], d_in[7], d_in[8],
                                            d_in[9], d_in[10], flags,
                                            qf, kf, vf, mbias, node_out, edge_out);
}

// Round 5
// 427.327 us; speedup vs baseline: 1.6667x; 1.6667x over previous
//
#include <hip/hip_runtime.h>
#include <hip/hip_bf16.h>
#include <stdint.h>

#define NN 512
#define HD 128

typedef __attribute__((ext_vector_type(8))) short bf16x8;
typedef __attribute__((ext_vector_type(4))) float f32x4;

static __device__ __forceinline__ float bf2f(unsigned short u) {
  union { uint32_t u32; float f; } cv; cv.u32 = ((uint32_t)u) << 16; return cv.f;
}
static __device__ __forceinline__ unsigned short f2bf(float f) {
  union { float f; uint32_t u; } cv; cv.f = f;
  return (unsigned short)((cv.u + 0x7FFFu + ((cv.u >> 16) & 1u)) >> 16);
}
// packed f32x2 -> bf16x2 (RNE), lo = first arg
static __device__ __forceinline__ uint32_t cvtpk(float lo, float hi) {
  uint32_t r;
  asm("v_cvt_pk_bf16_f32 %0, %1, %2" : "=v"(r) : "v"(lo), "v"(hi));
  return r;
}

struct DetectArgs { const uint16_t* p[10]; int n[10]; };

// Per-tensor dtype sniffing (flags[ti]=1 -> fp32, 0 -> bf16).
__global__ __launch_bounds__(256) void detect_kernel(DetectArgs a, int* __restrict__ flags) {
  __shared__ int acc[256];
  const int ti = blockIdx.x;
  int n = a.n[ti]; if (n > 2048) n = 2048;
  int g = 0;
  for (int w = threadIdx.x; w < n; w += 256) {
    uint16_t v = a.p[ti][w];
    int e = (v >> 7) & 0xFF;
    g += (v == 0u || (e >= 90 && e <= 133)) ? 1 : 0;
  }
  acc[threadIdx.x] = g;
  __syncthreads();
  for (int s = 128; s > 0; s >>= 1) {
    if (threadIdx.x < s) acc[threadIdx.x] += acc[threadIdx.x + s];
    __syncthreads();
  }
  if (threadIdx.x == 0) flags[ti] = (acc[0] * 10 < n * 9) ? 1 : 0;
}

// blocks 0..3: mask bias (verified by R4's node pass). blocks 4..7: Weo frag
// table (16 KB) in workspace -- block-invariant, so gat_main reads it via
// L1/L2 instead of spending 16 KB LDS per block. Math identical to R3's
// verified in-LDS phase-B build.
__global__ __launch_bounds__(256) void prep_kernel(const uint32_t* __restrict__ raw,
                                                   float* __restrict__ mbias, int count,
                                                   const void* __restrict__ Weop,
                                                   const int* __restrict__ flags,
                                                   uint16_t* __restrict__ w2f) {
  if (blockIdx.x < 4) {
    int inspect = count >> 2; if (inspect > 256) inspect = 256;
    bool ok_i32 = true, ok_f32 = true, ok_bf16 = true;
    #pragma unroll 1
    for (int w = 0; w < inspect; ++w) {
      uint32_t v = raw[w];
      if (v > 1u) ok_i32 = false;
      if (!(v == 0u || v == 0x3F800000u)) ok_f32 = false;
      uint32_t lo = v & 0xFFFFu, hi = v >> 16;
      if (!((lo == 0u || lo == 0x3F80u) && (hi == 0u || hi == 0x3F80u))) ok_bf16 = false;
    }
    int idx = blockIdx.x * 256 + threadIdx.x;
    if (idx < count) {
      bool on;
      if (ok_i32 || ok_f32) on = raw[idx] != 0u;
      else if (ok_bf16)     on = ((const uint16_t*)raw)[idx] != 0u;
      else                  on = ((const uint8_t*)raw)[idx] != 0u;
      mbias[idx] = on ? 0.0f : -1e30f;
    }
  } else {
    const int slot = (blockIdx.x - 4) * 256 + threadIdx.x;   // 0..1023
    const int t2 = slot >> 8, s = (slot >> 6) & 3, ln = slot & 63;
    const int c = t2 * 16 + (ln & 15);
    const int k0 = s * 32 + ((ln >> 4) & 3) * 8;
    const int f_Weo = flags[8];
    bf16x8 fr;
    if (f_Weo) {
      const float* W = (const float*)Weop;
      #pragma unroll
      for (int e = 0; e < 8; ++e) fr[e] = (short)f2bf(W[(k0 + e) * 64 + c]);
    } else {
      const uint16_t* W = (const uint16_t*)Weop;
      #pragma unroll
      for (int e = 0; e < 8; ++e) fr[e] = (short)W[(k0 + e) * 64 + c];
    }
    *(bf16x8*)&w2f[slot * 8] = fr;
  }
}

// qkv = x @ Wqkv + bqkv ; q linear, k PERMUTED within-row ((c&15)*8 + c>>4) so
// gat_main's frag gather is one bf16x8 load, v TRANSPOSED (vT[b][c][j]) so the
// node MFMA B-fragments are contiguous bf16x8 loads.
__global__ __launch_bounds__(128) void qkv_kernel(const void* __restrict__ xp,
                                                  const void* __restrict__ Wp,
                                                  const void* __restrict__ bp,
                                                  const int* __restrict__ flags,
                                                  uint16_t* __restrict__ qf,
                                                  uint16_t* __restrict__ kf,
                                                  uint16_t* __restrict__ vf) {
  const int f_x = flags[0], f_W = flags[2], f_b = flags[3];
  const int row = blockIdx.x;
  const int t = threadIdx.x;
  __shared__ float xs[HD];
  xs[t] = f_x ? ((const float*)xp)[row * HD + t] : bf2f(((const uint16_t*)xp)[row * HD + t]);
  __syncthreads();
  float aq = 0.f, ak = 0.f, av = 0.f;
  if (f_W) {
    const float* W = (const float*)Wp;
    #pragma unroll 4
    for (int kk = 0; kk < HD; ++kk) {
      float xv = xs[kk]; const float* wr = W + kk * 384;
      aq = fmaf(xv, wr[t], aq);
      ak = fmaf(xv, wr[128 + t], ak);
      av = fmaf(xv, wr[256 + t], av);
    }
  } else {
    const uint16_t* W = (const uint16_t*)Wp;
    #pragma unroll 4
    for (int kk = 0; kk < HD; ++kk) {
      float xv = xs[kk]; const uint16_t* wr = W + kk * 384;
      aq = fmaf(xv, bf2f(wr[t]), aq);
      ak = fmaf(xv, bf2f(wr[128 + t]), ak);
      av = fmaf(xv, bf2f(wr[256 + t]), av);
    }
  }
  float bq = f_b ? ((const float*)bp)[t]       : bf2f(((const uint16_t*)bp)[t]);
  float bk = f_b ? ((const float*)bp)[128 + t] : bf2f(((const uint16_t*)bp)[128 + t]);
  float bv = f_b ? ((const float*)bp)[256 + t] : bf2f(((const uint16_t*)bp)[256 + t]);
  qf[row * HD + t] = f2bf(aq + bq);
  kf[row * HD + ((t & 15) << 3) + (t >> 4)] = f2bf(ak + bk);
  vf[((size_t)((row >> 9) * HD + t)) * NN + (row & (NN - 1))] = f2bf(av + bv);
}

// One block per (b,i); 8 waves, wave w owns bands {w, w+8, w+16, w+24}.
// R5 = composition of VERIFIED pieces only. R3's half-K band body (stride-72
// raw tile, tl^quad swizzle, BLf logit tile, 16-row staging) passed on HW;
// R2's LDS B1f reads passed on HW. No register fragment hoards (R3's spill
// lesson): B1 frags read from LDS per use, B2 frags read from global w2f per
// use. LDS 49 KB -> 3 blocks/CU (24 waves vs R2's 16); launch_bounds(512,6)
// caps VGPR at ~85 (body needs ~66, R2's was 60 -> no spill expected).
__global__ __launch_bounds__(512, 6) void gat_main_kernel(
    const void* __restrict__ eap,
    const void* __restrict__ Wep,  const void* __restrict__ bep,
    const void* __restrict__ Wnop, const void* __restrict__ bnop,
    const void* __restrict__ beop,
    const int* __restrict__ flags,
    const uint16_t* __restrict__ qf, const uint16_t* __restrict__ kf,
    const uint16_t* __restrict__ vf, const uint16_t* __restrict__ w2f,
    const float* __restrict__ mbias,
    float* __restrict__ node_out, float* __restrict__ edge_out) {
  const int tid = threadIdx.x;
  const int w = tid >> 6, lane = tid & 63;
  const int l15 = lane & 15, quad = lane >> 4;
  const int bb = blockIdx.x >> 9;
  const int i  = blockIdx.x & (NN - 1);
  const int f_ea = flags[1], f_We = flags[4], f_be = flags[5];
  const int f_Wno = flags[6], f_bno = flags[7], f_beo = flags[9];

  __shared__ __align__(16) uint16_t B1f[8 * 2 * 64 * 8];   // We*q frags 16 KB
  __shared__ __align__(16) uint16_t BLf[4 * 64 * 8];       // logit tile 4 KB
  __shared__ __align__(16) uint16_t pool[8 * 1152];        // per-wave 16x72 u16, 18432 B
  __shared__ __align__(16) uint16_t att_s[8 * 520];        // [h][j] pad -> 8320 B
  __shared__ __align__(16) float q_s[HD];
  __shared__ __align__(16) float beq_s[HD];
  __shared__ __align__(16) float beo_s[64];
  __shared__ __align__(16) float node_s[HD];

  if (tid < HD) q_s[tid] = bf2f(qf[(bb * NN + i) * HD + tid]);
  if (tid >= 128 && tid < 192) {
    int c = tid - 128;
    beo_s[c] = f_beo ? ((const float*)beop)[c] : bf2f(((const uint16_t*)beop)[c]);
  }
  // logit head-indicator tile (R3-verified): B[k][h] = (k>>4 == h)
  if (tid < 256) {
    const int s = tid >> 6, ln = tid & 63;
    const int head = s * 2 + ((ln >> 5) & 1);
    const short v = ((ln & 15) == head) ? (short)0x3F80 : (short)0;
    bf16x8 fr;
    #pragma unroll
    for (int e = 0; e < 8; ++e) fr[e] = v;
    *(bf16x8*)&BLf[(s * 64 + ln) * 8] = fr;
  }
  __syncthreads();

  if (tid < HD) {
    float b = f_be ? ((const float*)bep)[tid] : bf2f(((const uint16_t*)bep)[tid]);
    beq_s[tid] = b * q_s[tid];
  }
  // build B1 frags (element = We[k][c]*q[c]); slot = t*128 + s*64 + ln (R2-verified)
  for (int slot = tid; slot < 1024; slot += 512) {
    const int t = slot >> 7, s = (slot >> 6) & 1, ln = slot & 63;
    const int c = t * 16 + (ln & 15);
    const int k0 = s * 32 + (ln >> 4) * 8;
    const float qc = q_s[c];
    bf16x8 fr;
    if (f_We) {
      const float* W = (const float*)Wep;
      #pragma unroll
      for (int e = 0; e < 8; ++e) fr[e] = (short)f2bf(W[(k0 + e) * HD + c] * qc);
    } else {
      const uint16_t* W = (const uint16_t*)Wep;
      #pragma unroll
      for (int e = 0; e < 8; ++e) fr[e] = (short)f2bf(bf2f(W[(k0 + e) * HD + c]) * qc);
    }
    *(bf16x8*)&B1f[slot * 8] = fr;
  }
  __syncthreads();

  const size_t io_base = (size_t)(bb * NN + i) * NN * 64;   // elements
  const uint16_t* kperm = kf + (size_t)bb * NN * HD;        // permuted rows
  const float* mrow = mbias + bb * NN;
  uint16_t* rws = pool + w * 1152;                          // 16 x 72 u16
  float*    fws = (float*)rws;                              // 16 x 36 f32 (alias)

  for (int band = w; band < 32; band += 8) {
    const int j0 = band * 16;
    const f32x4 mr = *(const f32x4*)(mrow + j0 + quad * 4);
    bf16x8 k8[4];
    #pragma unroll
    for (int r = 0; r < 4; ++r)
      k8[r] = *(const bf16x8*)(kperm + (size_t)(j0 + quad * 4 + r) * HD + l15 * 8);

    // ---- A1 fragments straight from global edge_attr ----
    bf16x8 A1[2];
    if (f_ea) {
      const float* ea = (const float*)eap + io_base + (size_t)(j0 + l15) * 64 + quad * 8;
      f32x4 e0 = __builtin_nontemporal_load((const f32x4*)ea);
      f32x4 e1 = __builtin_nontemporal_load((const f32x4*)(ea + 4));
      f32x4 e2 = __builtin_nontemporal_load((const f32x4*)(ea + 32));
      f32x4 e3 = __builtin_nontemporal_load((const f32x4*)(ea + 36));
      union { bf16x8 v; uint32_t u[4]; } c0, c1;
      c0.u[0] = cvtpk(e0[0], e0[1]); c0.u[1] = cvtpk(e0[2], e0[3]);
      c0.u[2] = cvtpk(e1[0], e1[1]); c0.u[3] = cvtpk(e1[2], e1[3]);
      c1.u[0] = cvtpk(e2[0], e2[1]); c1.u[1] = cvtpk(e2[2], e2[3]);
      c1.u[2] = cvtpk(e3[0], e3[1]); c1.u[3] = cvtpk(e3[2], e3[3]);
      A1[0] = c0.v; A1[1] = c1.v;
    } else {
      const uint16_t* ea = (const uint16_t*)eap + io_base + (size_t)(j0 + l15) * 64 + quad * 8;
      A1[0] = __builtin_nontemporal_load((const bf16x8*)ea);
      A1[1] = __builtin_nontemporal_load((const bf16x8*)(ea + 32));
    }

    f32x4 acc2[4];
    #pragma unroll
    for (int t2 = 0; t2 < 4; ++t2) {
      const float bv = beo_s[t2 * 16 + l15];
      acc2[t2] = (f32x4){bv, bv, bv, bv};
    }
    f32x4 aL = {0.f, 0.f, 0.f, 0.f};

    // ---- two K-halves (R3-verified body) ----
    #pragma unroll
    for (int h = 0; h < 2; ++h) {
      // GEMM1 half: tiles t = h*4 .. h*4+3 ; raw = k .* e_q -> swizzled LDS
      #pragma unroll
      for (int tl = 0; tl < 4; ++tl) {
        const int t = h * 4 + tl;
        const float bv = beq_s[t * 16 + l15];
        f32x4 a = {bv, bv, bv, bv};
        a = __builtin_amdgcn_mfma_f32_16x16x32_bf16(
              A1[0], *(const bf16x8*)&B1f[(t * 2 + 0) * 512 + lane * 8], a, 0, 0, 0);
        a = __builtin_amdgcn_mfma_f32_16x16x32_bf16(
              A1[1], *(const bf16x8*)&B1f[(t * 2 + 1) * 512 + lane * 8], a, 0, 0, 0);
        const float v0 = a[0] * bf2f((unsigned short)k8[0][t]);
        const float v1 = a[1] * bf2f((unsigned short)k8[1][t]);
        const float v2 = a[2] * bf2f((unsigned short)k8[2][t]);
        const float v3 = a[3] * bf2f((unsigned short)k8[3][t]);
        const uint32_t p01 = cvtpk(v0, v1), p23 = cvtpk(v2, v3);
        uint16_t* rp = &rws[(tl ^ quad) * 16 + l15];
        rp[(quad * 4 + 0) * 72] = (uint16_t)p01;
        rp[(quad * 4 + 1) * 72] = (uint16_t)(p01 >> 16);
        rp[(quad * 4 + 2) * 72] = (uint16_t)p23;
        rp[(quad * 4 + 3) * 72] = (uint16_t)(p23 >> 16);
      }
      // A2 frags (un-swizzle); accumulate logits + GEMM2
      #pragma unroll
      for (int sl = 0; sl < 2; ++sl) {
        const int s = h * 2 + sl;
        const int blk = (sl * 2 + (quad >> 1)) ^ (l15 >> 2);
        const bf16x8 A2 = *(const bf16x8*)&rws[l15 * 72 + blk * 16 + (quad & 1) * 8];
        aL = __builtin_amdgcn_mfma_f32_16x16x32_bf16(
               A2, *(const bf16x8*)&BLf[(s * 64 + lane) * 8], aL, 0, 0, 0);
        #pragma unroll
        for (int t2 = 0; t2 < 4; ++t2)
          acc2[t2] = __builtin_amdgcn_mfma_f32_16x16x32_bf16(
                       A2, *(const bf16x8*)&w2f[(size_t)((t2 * 4 + s) * 64 + lane) * 8],
                       acc2[t2], 0, 0, 0);
      }
    }

    // ---- logits (R3-verified) ----
    if (l15 < 8) {
      #pragma unroll
      for (int r = 0; r < 4; ++r)
        att_s[l15 * 520 + (j0 + quad * 4 + r)] = f2bf(aL[r] * 0.25f + mr[r]);
    }

    // ---- edge_out staging + full-line stores (R3-verified) ----
    #pragma unroll
    for (int ch = 0; ch < 2; ++ch) {
      #pragma unroll
      for (int t2l = 0; t2l < 2; ++t2l) {
        const int t2 = ch * 2 + t2l;
        #pragma unroll
        for (int r = 0; r < 4; ++r)
          fws[(quad * 4 + r) * 36 + t2l * 16 + l15] = acc2[t2][r];
      }
      #pragma unroll
      for (int rg = 0; rg < 2; ++rg) {
        const int row = rg * 8 + (lane >> 3);
        f32x4 vv = *(const f32x4*)&fws[row * 36 + (lane & 7) * 4];
        __builtin_nontemporal_store(vv,
            (f32x4*)(edge_out + io_base + (size_t)(j0 + row) * 64 + ch * 32) + (lane & 7));
      }
    }
  }
  __syncthreads();

  // ---- softmax over j: wave w owns head w; shuffle reductions ----
  {
    float vals[8];
    float m = -3.4e38f;
    #pragma unroll
    for (int it = 0; it < 8; ++it)
      m = fmaxf(m, bf2f(att_s[w * 520 + it * 64 + lane]));
    #pragma unroll
    for (int off = 32; off; off >>= 1) m = fmaxf(m, __shfl_xor(m, off));
    float ssum = 0.f;
    #pragma unroll
    for (int it = 0; it < 8; ++it) {
      float v = __expf(bf2f(att_s[w * 520 + it * 64 + lane]) - m);
      vals[it] = v; ssum += v;
    }
    #pragma unroll
    for (int off = 32; off; off >>= 1) ssum += __shfl_xor(ssum, off);
    const float inv = 1.0f / ssum;
    #pragma unroll
    for (int it = 0; it < 8; ++it)
      att_s[w * 520 + it * 64 + lane] = f2bf(vals[it] * inv);
  }
  __syncthreads();   // all heads final; pool free for reductions

  // ---- node = att @ v via MFMA: wave w covers j in [w*64, w*64+64) ----
  {
    f32x4 nacc[8];
    #pragma unroll
    for (int t = 0; t < 8; ++t) nacc[t] = (f32x4){0.f, 0.f, 0.f, 0.f};
    const uint16_t* vbase = vf + (size_t)bb * HD * NN;
    #pragma unroll
    for (int ks = 0; ks < 2; ++ks) {
      const int k0 = w * 64 + ks * 32;
      const bf16x8 Af = *(const bf16x8*)&att_s[(l15 & 7) * 520 + k0 + quad * 8];
      #pragma unroll
      for (int t = 0; t < 8; ++t) {
        const bf16x8 Bf = *(const bf16x8*)(vbase + (size_t)(t * 16 + l15) * NN + k0 + quad * 8);
        nacc[t] = __builtin_amdgcn_mfma_f32_16x16x32_bf16(Af, Bf, nacc[t], 0, 0, 0);
      }
    }
    float* red = (float*)pool;             // 8 x 128 f32 = 4 KB
    #pragma unroll
    for (int t = 0; t < 8; ++t)
      if (quad == (t >> 2)) red[w * 128 + t * 16 + l15] = nacc[t][t & 3];
    __syncthreads();
    if (tid < HD) {
      float s = 0.f;
      #pragma unroll
      for (int w2 = 0; w2 < 8; ++w2) s += red[w2 * 128 + tid];
      node_s[tid] = s;
    }
    __syncthreads();
  }

  // ---- node_out = node @ Wno + bno (512-thread split GEMV) ----
  {
    const int c = tid & 127, part = tid >> 7;
    float acc = 0.f;
    if (f_Wno) {
      const float* W = (const float*)Wnop;
      #pragma unroll 8
      for (int kk = part * 32; kk < part * 32 + 32; ++kk)
        acc = fmaf(node_s[kk], W[kk * HD + c], acc);
    } else {
      const uint16_t* W = (const uint16_t*)Wnop;
      #pragma unroll 8
      for (int kk = part * 32; kk < part * 32 + 32; ++kk)
        acc = fmaf(node_s[kk], bf2f(W[kk * HD + c]), acc);
    }
    float* red2 = (float*)pool + 1024;     // 512 f32 = 2 KB
    red2[tid] = acc;
    __syncthreads();
    if (tid < HD) {
      float b = f_bno ? ((const float*)bnop)[tid] : bf2f(((const uint16_t*)bnop)[tid]);
      float r = red2[tid] + red2[128 + tid] + red2[256 + tid] + red2[384 + tid] + b;
      node_out[(bb * NN + i) * HD + tid] = r;
    }
  }
}

extern "C" void kernel_launch(void* const* d_in, const int* in_sizes, int n_in,
                              void* d_out, int out_size, void* d_ws, size_t ws_size,
                              hipStream_t stream) {
  const int b = in_sizes[0] / (NN * HD);   // = 2
  const int rows = b * NN;                 // = 1024

  int*   flags = (int*)d_ws;                                        // 16 ints
  float* mbias = (float*)((char*)d_ws + 64);                        // rows floats
  uint16_t* qf = (uint16_t*)((char*)d_ws + 64 + 4096);
  uint16_t* kf = qf + (size_t)rows * HD;
  uint16_t* vf = kf + (size_t)rows * HD;                            // transposed [b][c][j]
  uint16_t* w2f = vf + (size_t)rows * HD;                           // Weo frag table 16 KB

  float* node_out = (float*)d_out;
  float* edge_out = node_out + (size_t)rows * HD;

  DetectArgs da;
  const int float_idx[10] = {0, 1, 3, 4, 5, 6, 7, 8, 9, 10};
  for (int t = 0; t < 10; ++t) {
    da.p[t] = (const uint16_t*)d_in[float_idx[t]];
    da.n[t] = in_sizes[float_idx[t]];
  }

  detect_kernel<<<10, 256, 0, stream>>>(da, flags);
  prep_kernel<<<8, 256, 0, stream>>>((const uint32_t*)d_in[2], mbias, rows,
                                     d_in[9], flags, w2f);
  qkv_kernel<<<rows, 128, 0, stream>>>(d_in[0], d_in[3], d_in[4], flags, qf, kf, vf);
  gat_main_kernel<<<rows, 512, 0, stream>>>(d_in[1], d_in[5], d_in[6], d_in[7], d_in[8],
                                            d_in[10], flags,
                                            qf, kf, vf, w2f, mbias, node_out, edge_out);
}

// Round 6
// 360.238 us; speedup vs baseline: 1.9771x; 1.1862x over previous
//
#include <hip/hip_runtime.h>
#include <hip/hip_bf16.h>
#include <stdint.h>

#define NN 512
#define HD 128

typedef __attribute__((ext_vector_type(8))) short bf16x8;
typedef __attribute__((ext_vector_type(4))) float f32x4;

static __device__ __forceinline__ float bf2f(unsigned short u) {
  union { uint32_t u32; float f; } cv; cv.u32 = ((uint32_t)u) << 16; return cv.f;
}
static __device__ __forceinline__ unsigned short f2bf(float f) {
  union { float f; uint32_t u; } cv; cv.f = f;
  return (unsigned short)((cv.u + 0x7FFFu + ((cv.u >> 16) & 1u)) >> 16);
}
// packed f32x2 -> bf16x2 (RNE), lo = first arg
static __device__ __forceinline__ uint32_t cvtpk(float lo, float hi) {
  uint32_t r;
  asm("v_cvt_pk_bf16_f32 %0, %1, %2" : "=v"(r) : "v"(lo), "v"(hi));
  return r;
}

struct DetectArgs { const uint16_t* p[10]; int n[10]; };

// Per-tensor dtype sniffing (flags[ti]=1 -> fp32, 0 -> bf16).
__global__ __launch_bounds__(256) void detect_kernel(DetectArgs a, int* __restrict__ flags) {
  __shared__ int acc[256];
  const int ti = blockIdx.x;
  int n = a.n[ti]; if (n > 2048) n = 2048;
  int g = 0;
  for (int w = threadIdx.x; w < n; w += 256) {
    uint16_t v = a.p[ti][w];
    int e = (v >> 7) & 0xFF;
    g += (v == 0u || (e >= 90 && e <= 133)) ? 1 : 0;
  }
  acc[threadIdx.x] = g;
  __syncthreads();
  for (int s = 128; s > 0; s >>= 1) {
    if (threadIdx.x < s) acc[threadIdx.x] += acc[threadIdx.x + s];
    __syncthreads();
  }
  if (threadIdx.x == 0) flags[ti] = (acc[0] * 10 < n * 9) ? 1 : 0;
}

// blocks 0..3: mask bias. blocks 4..7: Weo frag table (16 KB) in workspace --
// block-invariant, so gat_main reads it via L1/L2 instead of spending 16 KB
// LDS per block. Math identical to R3's verified in-LDS phase-B build.
__global__ __launch_bounds__(256) void prep_kernel(const uint32_t* __restrict__ raw,
                                                   float* __restrict__ mbias, int count,
                                                   const void* __restrict__ Weop,
                                                   const int* __restrict__ flags,
                                                   uint16_t* __restrict__ w2f) {
  if (blockIdx.x < 4) {
    int inspect = count >> 2; if (inspect > 256) inspect = 256;
    bool ok_i32 = true, ok_f32 = true, ok_bf16 = true;
    #pragma unroll 1
    for (int w = 0; w < inspect; ++w) {
      uint32_t v = raw[w];
      if (v > 1u) ok_i32 = false;
      if (!(v == 0u || v == 0x3F800000u)) ok_f32 = false;
      uint32_t lo = v & 0xFFFFu, hi = v >> 16;
      if (!((lo == 0u || lo == 0x3F80u) && (hi == 0u || hi == 0x3F80u))) ok_bf16 = false;
    }
    int idx = blockIdx.x * 256 + threadIdx.x;
    if (idx < count) {
      bool on;
      if (ok_i32 || ok_f32) on = raw[idx] != 0u;
      else if (ok_bf16)     on = ((const uint16_t*)raw)[idx] != 0u;
      else                  on = ((const uint8_t*)raw)[idx] != 0u;
      mbias[idx] = on ? 0.0f : -1e30f;
    }
  } else {
    const int slot = (blockIdx.x - 4) * 256 + threadIdx.x;   // 0..1023
    const int t2 = slot >> 8, s = (slot >> 6) & 3, ln = slot & 63;
    const int c = t2 * 16 + (ln & 15);
    const int k0 = s * 32 + ((ln >> 4) & 3) * 8;
    const int f_Weo = flags[8];
    bf16x8 fr;
    if (f_Weo) {
      const float* W = (const float*)Weop;
      #pragma unroll
      for (int e = 0; e < 8; ++e) fr[e] = (short)f2bf(W[(k0 + e) * 64 + c]);
    } else {
      const uint16_t* W = (const uint16_t*)Weop;
      #pragma unroll
      for (int e = 0; e < 8; ++e) fr[e] = (short)W[(k0 + e) * 64 + c];
    }
    *(bf16x8*)&w2f[slot * 8] = fr;
  }
}

// qkv = x @ Wqkv + bqkv ; q linear, k PERMUTED within-row ((c&15)*8 + c>>4) so
// gat_main's frag gather is one bf16x8 load, v TRANSPOSED (vT[b][c][j]) so the
// node MFMA B-fragments are contiguous bf16x8 loads.
__global__ __launch_bounds__(128) void qkv_kernel(const void* __restrict__ xp,
                                                  const void* __restrict__ Wp,
                                                  const void* __restrict__ bp,
                                                  const int* __restrict__ flags,
                                                  uint16_t* __restrict__ qf,
                                                  uint16_t* __restrict__ kf,
                                                  uint16_t* __restrict__ vf) {
  const int f_x = flags[0], f_W = flags[2], f_b = flags[3];
  const int row = blockIdx.x;
  const int t = threadIdx.x;
  __shared__ float xs[HD];
  xs[t] = f_x ? ((const float*)xp)[row * HD + t] : bf2f(((const uint16_t*)xp)[row * HD + t]);
  __syncthreads();
  float aq = 0.f, ak = 0.f, av = 0.f;
  if (f_W) {
    const float* W = (const float*)Wp;
    #pragma unroll 4
    for (int kk = 0; kk < HD; ++kk) {
      float xv = xs[kk]; const float* wr = W + kk * 384;
      aq = fmaf(xv, wr[t], aq);
      ak = fmaf(xv, wr[128 + t], ak);
      av = fmaf(xv, wr[256 + t], av);
    }
  } else {
    const uint16_t* W = (const uint16_t*)Wp;
    #pragma unroll 4
    for (int kk = 0; kk < HD; ++kk) {
      float xv = xs[kk]; const uint16_t* wr = W + kk * 384;
      aq = fmaf(xv, bf2f(wr[t]), aq);
      ak = fmaf(xv, bf2f(wr[128 + t]), ak);
      av = fmaf(xv, bf2f(wr[256 + t]), av);
    }
  }
  float bq = f_b ? ((const float*)bp)[t]       : bf2f(((const uint16_t*)bp)[t]);
  float bk = f_b ? ((const float*)bp)[128 + t] : bf2f(((const uint16_t*)bp)[128 + t]);
  float bv = f_b ? ((const float*)bp)[256 + t] : bf2f(((const uint16_t*)bp)[256 + t]);
  qf[row * HD + t] = f2bf(aq + bq);
  kf[row * HD + ((t & 15) << 3) + (t >> 4)] = f2bf(ak + bk);
  vf[((size_t)((row >> 9) * HD + t)) * NN + (row & (NN - 1))] = f2bf(av + bv);
}

// One block per (b,i); 8 waves, wave w owns bands {w, w+8, w+16, w+24}.
// R6 = R5 body (HW-verified correct) with ONE change: launch_bounds(512,6) ->
// (512,4). R5 post-mortem: the ",6" VGPR cap (~85) made the allocator emit a
// 40-VGPR + scratch-spill kernel (FETCH 189MB vs 69 compulsory, WRITE 226 vs
// 131 -> +215MB spill ≈ the whole 179-vs-101µs regression; same signature as
// R3). ",4" is R2's empirically spill-free config (VGPR=60, exact-compulsory
// traffic). LDS 49KB still allows 3 blocks/CU if VGPR <= 85.
__global__ __launch_bounds__(512, 4) void gat_main_kernel(
    const void* __restrict__ eap,
    const void* __restrict__ Wep,  const void* __restrict__ bep,
    const void* __restrict__ Wnop, const void* __restrict__ bnop,
    const void* __restrict__ beop,
    const int* __restrict__ flags,
    const uint16_t* __restrict__ qf, const uint16_t* __restrict__ kf,
    const uint16_t* __restrict__ vf, const uint16_t* __restrict__ w2f,
    const float* __restrict__ mbias,
    float* __restrict__ node_out, float* __restrict__ edge_out) {
  const int tid = threadIdx.x;
  const int w = tid >> 6, lane = tid & 63;
  const int l15 = lane & 15, quad = lane >> 4;
  const int bb = blockIdx.x >> 9;
  const int i  = blockIdx.x & (NN - 1);
  const int f_ea = flags[1], f_We = flags[4], f_be = flags[5];
  const int f_Wno = flags[6], f_bno = flags[7], f_beo = flags[9];

  __shared__ __align__(16) uint16_t B1f[8 * 2 * 64 * 8];   // We*q frags 16 KB
  __shared__ __align__(16) uint16_t BLf[4 * 64 * 8];       // logit tile 4 KB
  __shared__ __align__(16) uint16_t pool[8 * 1152];        // per-wave 16x72 u16, 18432 B
  __shared__ __align__(16) uint16_t att_s[8 * 520];        // [h][j] pad -> 8320 B
  __shared__ __align__(16) float q_s[HD];
  __shared__ __align__(16) float beq_s[HD];
  __shared__ __align__(16) float beo_s[64];
  __shared__ __align__(16) float node_s[HD];

  if (tid < HD) q_s[tid] = bf2f(qf[(bb * NN + i) * HD + tid]);
  if (tid >= 128 && tid < 192) {
    int c = tid - 128;
    beo_s[c] = f_beo ? ((const float*)beop)[c] : bf2f(((const uint16_t*)beop)[c]);
  }
  // logit head-indicator tile: B[k][h] = (k>>4 == h)
  if (tid < 256) {
    const int s = tid >> 6, ln = tid & 63;
    const int head = s * 2 + ((ln >> 5) & 1);
    const short v = ((ln & 15) == head) ? (short)0x3F80 : (short)0;
    bf16x8 fr;
    #pragma unroll
    for (int e = 0; e < 8; ++e) fr[e] = v;
    *(bf16x8*)&BLf[(s * 64 + ln) * 8] = fr;
  }
  __syncthreads();

  if (tid < HD) {
    float b = f_be ? ((const float*)bep)[tid] : bf2f(((const uint16_t*)bep)[tid]);
    beq_s[tid] = b * q_s[tid];
  }
  // build B1 frags (element = We[k][c]*q[c]); slot = t*128 + s*64 + ln
  for (int slot = tid; slot < 1024; slot += 512) {
    const int t = slot >> 7, s = (slot >> 6) & 1, ln = slot & 63;
    const int c = t * 16 + (ln & 15);
    const int k0 = s * 32 + (ln >> 4) * 8;
    const float qc = q_s[c];
    bf16x8 fr;
    if (f_We) {
      const float* W = (const float*)Wep;
      #pragma unroll
      for (int e = 0; e < 8; ++e) fr[e] = (short)f2bf(W[(k0 + e) * HD + c] * qc);
    } else {
      const uint16_t* W = (const uint16_t*)Wep;
      #pragma unroll
      for (int e = 0; e < 8; ++e) fr[e] = (short)f2bf(bf2f(W[(k0 + e) * HD + c]) * qc);
    }
    *(bf16x8*)&B1f[slot * 8] = fr;
  }
  __syncthreads();

  const size_t io_base = (size_t)(bb * NN + i) * NN * 64;   // elements
  const uint16_t* kperm = kf + (size_t)bb * NN * HD;        // permuted rows
  const float* mrow = mbias + bb * NN;
  uint16_t* rws = pool + w * 1152;                          // 16 x 72 u16
  float*    fws = (float*)rws;                              // 16 x 36 f32 (alias)

  for (int band = w; band < 32; band += 8) {
    const int j0 = band * 16;
    const f32x4 mr = *(const f32x4*)(mrow + j0 + quad * 4);
    bf16x8 k8[4];
    #pragma unroll
    for (int r = 0; r < 4; ++r)
      k8[r] = *(const bf16x8*)(kperm + (size_t)(j0 + quad * 4 + r) * HD + l15 * 8);

    // ---- A1 fragments straight from global edge_attr ----
    bf16x8 A1[2];
    if (f_ea) {
      const float* ea = (const float*)eap + io_base + (size_t)(j0 + l15) * 64 + quad * 8;
      f32x4 e0 = __builtin_nontemporal_load((const f32x4*)ea);
      f32x4 e1 = __builtin_nontemporal_load((const f32x4*)(ea + 4));
      f32x4 e2 = __builtin_nontemporal_load((const f32x4*)(ea + 32));
      f32x4 e3 = __builtin_nontemporal_load((const f32x4*)(ea + 36));
      union { bf16x8 v; uint32_t u[4]; } c0, c1;
      c0.u[0] = cvtpk(e0[0], e0[1]); c0.u[1] = cvtpk(e0[2], e0[3]);
      c0.u[2] = cvtpk(e1[0], e1[1]); c0.u[3] = cvtpk(e1[2], e1[3]);
      c1.u[0] = cvtpk(e2[0], e2[1]); c1.u[1] = cvtpk(e2[2], e2[3]);
      c1.u[2] = cvtpk(e3[0], e3[1]); c1.u[3] = cvtpk(e3[2], e3[3]);
      A1[0] = c0.v; A1[1] = c1.v;
    } else {
      const uint16_t* ea = (const uint16_t*)eap + io_base + (size_t)(j0 + l15) * 64 + quad * 8;
      A1[0] = __builtin_nontemporal_load((const bf16x8*)ea);
      A1[1] = __builtin_nontemporal_load((const bf16x8*)(ea + 32));
    }

    f32x4 acc2[4];
    #pragma unroll
    for (int t2 = 0; t2 < 4; ++t2) {
      const float bv = beo_s[t2 * 16 + l15];
      acc2[t2] = (f32x4){bv, bv, bv, bv};
    }
    f32x4 aL = {0.f, 0.f, 0.f, 0.f};

    // ---- two K-halves ----
    #pragma unroll
    for (int h = 0; h < 2; ++h) {
      // GEMM1 half: tiles t = h*4 .. h*4+3 ; raw = k .* e_q -> swizzled LDS
      #pragma unroll
      for (int tl = 0; tl < 4; ++tl) {
        const int t = h * 4 + tl;
        const float bv = beq_s[t * 16 + l15];
        f32x4 a = {bv, bv, bv, bv};
        a = __builtin_amdgcn_mfma_f32_16x16x32_bf16(
              A1[0], *(const bf16x8*)&B1f[(t * 2 + 0) * 512 + lane * 8], a, 0, 0, 0);
        a = __builtin_amdgcn_mfma_f32_16x16x32_bf16(
              A1[1], *(const bf16x8*)&B1f[(t * 2 + 1) * 512 + lane * 8], a, 0, 0, 0);
        const float v0 = a[0] * bf2f((unsigned short)k8[0][t]);
        const float v1 = a[1] * bf2f((unsigned short)k8[1][t]);
        const float v2 = a[2] * bf2f((unsigned short)k8[2][t]);
        const float v3 = a[3] * bf2f((unsigned short)k8[3][t]);
        const uint32_t p01 = cvtpk(v0, v1), p23 = cvtpk(v2, v3);
        uint16_t* rp = &rws[(tl ^ quad) * 16 + l15];
        rp[(quad * 4 + 0) * 72] = (uint16_t)p01;
        rp[(quad * 4 + 1) * 72] = (uint16_t)(p01 >> 16);
        rp[(quad * 4 + 2) * 72] = (uint16_t)p23;
        rp[(quad * 4 + 3) * 72] = (uint16_t)(p23 >> 16);
      }
      // A2 frags (un-swizzle); accumulate logits + GEMM2
      #pragma unroll
      for (int sl = 0; sl < 2; ++sl) {
        const int s = h * 2 + sl;
        const int blk = (sl * 2 + (quad >> 1)) ^ (l15 >> 2);
        const bf16x8 A2 = *(const bf16x8*)&rws[l15 * 72 + blk * 16 + (quad & 1) * 8];
        aL = __builtin_amdgcn_mfma_f32_16x16x32_bf16(
               A2, *(const bf16x8*)&BLf[(s * 64 + lane) * 8], aL, 0, 0, 0);
        #pragma unroll
        for (int t2 = 0; t2 < 4; ++t2)
          acc2[t2] = __builtin_amdgcn_mfma_f32_16x16x32_bf16(
                       A2, *(const bf16x8*)&w2f[(size_t)((t2 * 4 + s) * 64 + lane) * 8],
                       acc2[t2], 0, 0, 0);
      }
    }

    // ---- logits ----
    if (l15 < 8) {
      #pragma unroll
      for (int r = 0; r < 4; ++r)
        att_s[l15 * 520 + (j0 + quad * 4 + r)] = f2bf(aL[r] * 0.25f + mr[r]);
    }

    // ---- edge_out staging + full-line stores ----
    #pragma unroll
    for (int ch = 0; ch < 2; ++ch) {
      #pragma unroll
      for (int t2l = 0; t2l < 2; ++t2l) {
        const int t2 = ch * 2 + t2l;
        #pragma unroll
        for (int r = 0; r < 4; ++r)
          fws[(quad * 4 + r) * 36 + t2l * 16 + l15] = acc2[t2][r];
      }
      #pragma unroll
      for (int rg = 0; rg < 2; ++rg) {
        const int row = rg * 8 + (lane >> 3);
        f32x4 vv = *(const f32x4*)&fws[row * 36 + (lane & 7) * 4];
        __builtin_nontemporal_store(vv,
            (f32x4*)(edge_out + io_base + (size_t)(j0 + row) * 64 + ch * 32) + (lane & 7));
      }
    }
  }
  __syncthreads();

  // ---- softmax over j: wave w owns head w; shuffle reductions ----
  {
    float vals[8];
    float m = -3.4e38f;
    #pragma unroll
    for (int it = 0; it < 8; ++it)
      m = fmaxf(m, bf2f(att_s[w * 520 + it * 64 + lane]));
    #pragma unroll
    for (int off = 32; off; off >>= 1) m = fmaxf(m, __shfl_xor(m, off));
    float ssum = 0.f;
    #pragma unroll
    for (int it = 0; it < 8; ++it) {
      float v = __expf(bf2f(att_s[w * 520 + it * 64 + lane]) - m);
      vals[it] = v; ssum += v;
    }
    #pragma unroll
    for (int off = 32; off; off >>= 1) ssum += __shfl_xor(ssum, off);
    const float inv = 1.0f / ssum;
    #pragma unroll
    for (int it = 0; it < 8; ++it)
      att_s[w * 520 + it * 64 + lane] = f2bf(vals[it] * inv);
  }
  __syncthreads();   // all heads final; pool free for reductions

  // ---- node = att @ v via MFMA: wave w covers j in [w*64, w*64+64) ----
  {
    f32x4 nacc[8];
    #pragma unroll
    for (int t = 0; t < 8; ++t) nacc[t] = (f32x4){0.f, 0.f, 0.f, 0.f};
    const uint16_t* vbase = vf + (size_t)bb * HD * NN;
    #pragma unroll
    for (int ks = 0; ks < 2; ++ks) {
      const int k0 = w * 64 + ks * 32;
      const bf16x8 Af = *(const bf16x8*)&att_s[(l15 & 7) * 520 + k0 + quad * 8];
      #pragma unroll
      for (int t = 0; t < 8; ++t) {
        const bf16x8 Bf = *(const bf16x8*)(vbase + (size_t)(t * 16 + l15) * NN + k0 + quad * 8);
        nacc[t] = __builtin_amdgcn_mfma_f32_16x16x32_bf16(Af, Bf, nacc[t], 0, 0, 0);
      }
    }
    float* red = (float*)pool;             // 8 x 128 f32 = 4 KB
    #pragma unroll
    for (int t = 0; t < 8; ++t)
      if (quad == (t >> 2)) red[w * 128 + t * 16 + l15] = nacc[t][t & 3];
    __syncthreads();
    if (tid < HD) {
      float s = 0.f;
      #pragma unroll
      for (int w2 = 0; w2 < 8; ++w2) s += red[w2 * 128 + tid];
      node_s[tid] = s;
    }
    __syncthreads();
  }

  // ---- node_out = node @ Wno + bno (512-thread split GEMV) ----
  {
    const int c = tid & 127, part = tid >> 7;
    float acc = 0.f;
    if (f_Wno) {
      const float* W = (const float*)Wnop;
      #pragma unroll 8
      for (int kk = part * 32; kk < part * 32 + 32; ++kk)
        acc = fmaf(node_s[kk], W[kk * HD + c], acc);
    } else {
      const uint16_t* W = (const uint16_t*)Wnop;
      #pragma unroll 8
      for (int kk = part * 32; kk < part * 32 + 32; ++kk)
        acc = fmaf(node_s[kk], bf2f(W[kk * HD + c]), acc);
    }
    float* red2 = (float*)pool + 1024;     // 512 f32 = 2 KB
    red2[tid] = acc;
    __syncthreads();
    if (tid < HD) {
      float b = f_bno ? ((const float*)bnop)[tid] : bf2f(((const uint16_t*)bnop)[tid]);
      float r = red2[tid] + red2[128 + tid] + red2[256 + tid] + red2[384 + tid] + b;
      node_out[(bb * NN + i) * HD + tid] = r;
    }
  }
}

extern "C" void kernel_launch(void* const* d_in, const int* in_sizes, int n_in,
                              void* d_out, int out_size, void* d_ws, size_t ws_size,
                              hipStream_t stream) {
  const int b = in_sizes[0] / (NN * HD);   // = 2
  const int rows = b * NN;                 // = 1024

  int*   flags = (int*)d_ws;                                        // 16 ints
  float* mbias = (float*)((char*)d_ws + 64);                        // rows floats
  uint16_t* qf = (uint16_t*)((char*)d_ws + 64 + 4096);
  uint16_t* kf = qf + (size_t)rows * HD;
  uint16_t* vf = kf + (size_t)rows * HD;                            // transposed [b][c][j]
  uint16_t* w2f = vf + (size_t)rows * HD;                           // Weo frag table 16 KB

  float* node_out = (float*)d_out;
  float* edge_out = node_out + (size_t)rows * HD;

  DetectArgs da;
  const int float_idx[10] = {0, 1, 3, 4, 5, 6, 7, 8, 9, 10};
  for (int t = 0; t < 10; ++t) {
    da.p[t] = (const uint16_t*)d_in[float_idx[t]];
    da.n[t] = in_sizes[float_idx[t]];
  }

  detect_kernel<<<10, 256, 0, stream>>>(da, flags);
  prep_kernel<<<8, 256, 0, stream>>>((const uint32_t*)d_in[2], mbias, rows,
                                     d_in[9], flags, w2f);
  qkv_kernel<<<rows, 128, 0, stream>>>(d_in[0], d_in[3], d_in[4], flags, qf, kf, vf);
  gat_main_kernel<<<rows, 512, 0, stream>>>(d_in[1], d_in[5], d_in[6], d_in[7], d_in[8],
                                            d_in[10], flags,
                                            qf, kf, vf, w2f, mbias, node_out, edge_out);
}